// Round 13
// baseline (3359.863 us; speedup 1.0000x reference)
//
#include <hip/hip_runtime.h>

#define NCA_ALPHA 0.1f

// r13 = r11 (best, 2515us) + register-resident L0 state.
// Each thread keeps its own 2x2x2 L0 group in 8 v4f registers across steps:
//   - centers (8 reads/step) come from regs
//   - intra-group neighbors (24 reads/step) come from regs (s[cell^{1,2,4}])
//   - L1's below-pool (8 reads/step) is summed from regs pre-update
// -> L0 LDS reads drop 72 -> 32 per thread-step. Registers == LDS copy at all
// times (same value written to both; cone-skipped waves leave both at 0; regs
// initialized from S0[0] after the input barrier). Two-phase update (nbv[8]
// from old state, then overwrite) avoids intra-group RAW. FLOP order per cell
// identical to r11 (a-1,a+1,b-1,b+1,d-1,d+1; pool in q-order).
//
// Light cones (exact, r11): L0 t: t0 [7,9] t1 [6,10] t2 [5,11] t3 [4,13]
// t4 [2,15] else full; L1 t: t0 {4} t1 [3,5] t2 [2,6] t3 [1,7] else full.
// Dead steps: L0 t<=12, L1 t<=13, L2 t>=1.
typedef float v2f __attribute__((ext_vector_type(2)));
typedef float v4f __attribute__((ext_vector_type(4)));

__device__ __forceinline__ v4f ld4(const float* p) { return *(const v4f*)p; }
__device__ __forceinline__ void st4(float* p, v4f v) { *(v4f*)p = v; }
__device__ __forceinline__ v2f vfma2(v2f a, v2f b, v2f c) {
  return __builtin_elementwise_fma(a, b, c);
}
__device__ __forceinline__ v4f vfma4(v4f a, v4f b, v4f c) {
  return __builtin_elementwise_fma(a, b, c);
}

// r11 swizzled indices (measured-best base)
__device__ __forceinline__ int ix0(int a, int b, int d) {
  return (((a * 16 + b) * 16 + d) * 4) ^ ((((a >> 1) ^ (b >> 1)) & 7) << 2);
}
__device__ __forceinline__ int ix1(int a, int b, int d) {
  return (((a * 8 + b) * 8 + d) * 4) ^ (((a ^ b) & 7) << 2);
}
__device__ __forceinline__ int ix2(int a, int b, int d) { return ((a * 4 + b) * 4 + d) * 4; }

// h[j] += vv * w[j] over 16 pairs; w is wave-uniform (s_load pairs), vv a splat.
__device__ __forceinline__ void fma_row16(v2f h[16], v2f vv, const float* __restrict__ w) {
  const v2f* wv = (const v2f*)w;
#pragma unroll
  for (int j = 0; j < 16; ++j) h[j] = vfma2(vv, wv[j], h[j]);
}

// 8 perception rows, accumulate-only (h pre-initialized with bias/fold).
__device__ __forceinline__ void p_rows(v2f h[16], v4f c4, v4f nb, const float* __restrict__ W1) {
  v4f m6 = {-6.0f, -6.0f, -6.0f, -6.0f};
  v4f lap = vfma4(m6, c4, nb);
  fma_row16(h, c4.xx, W1 + 0);
  fma_row16(h, lap.xx, W1 + 32);
  fma_row16(h, c4.yy, W1 + 64);
  fma_row16(h, lap.yy, W1 + 96);
  fma_row16(h, c4.zz, W1 + 128);
  fma_row16(h, lap.zz, W1 + 160);
  fma_row16(h, c4.ww, W1 + 192);
  fma_row16(h, lap.ww, W1 + 224);
}

// Same but row 0 initializes h from acc (saves the 16-pair copy).
__device__ __forceinline__ void p_rows_init(v2f h[16], const v2f acc[16], v4f c4, v4f nb,
                                            const float* __restrict__ W1) {
  v4f m6 = {-6.0f, -6.0f, -6.0f, -6.0f};
  v4f lap = vfma4(m6, c4, nb);
  const v2f* w0 = (const v2f*)W1;
#pragma unroll
  for (int j = 0; j < 16; ++j) h[j] = vfma2(c4.xx, w0[j], acc[j]);
  fma_row16(h, lap.xx, W1 + 32);
  fma_row16(h, c4.yy, W1 + 64);
  fma_row16(h, lap.yy, W1 + 96);
  fma_row16(h, c4.zz, W1 + 128);
  fma_row16(h, lap.zz, W1 + 160);
  fma_row16(h, c4.ww, W1 + 192);
  fma_row16(h, lap.ww, W1 + 224);
}

// relu + (32x4) second layer + residual + clip. Accumulation order per output
// identical to all passing versions (bias-init, ascending hidden index).
__device__ __forceinline__ v4f mlp_tail(const v2f h[16], const float* __restrict__ W2,
                                        const float* __restrict__ B2, v4f c4) {
  const v2f* w = (const v2f*)W2;
  const v2f* bv = (const v2f*)B2;
  v2f d01 = bv[0], d23 = bv[1];
  v2f z = {0.0f, 0.0f};
#pragma unroll
  for (int j = 0; j < 16; ++j) {
    v2f hr = __builtin_elementwise_max(h[j], z);
    d01 = vfma2(hr.xx, w[4 * j + 0], d01);
    d23 = vfma2(hr.xx, w[4 * j + 1], d23);
    d01 = vfma2(hr.yy, w[4 * j + 2], d01);
    d23 = vfma2(hr.yy, w[4 * j + 3], d23);
  }
  v4f dv = {d01.x, d01.y, d23.x, d23.y};
  v4f al = {NCA_ALPHA, NCA_ALPHA, NCA_ALPHA, NCA_ALPHA};
  v4f one = {1.0f, 1.0f, 1.0f, 1.0f};
  v4f mone = {-1.0f, -1.0f, -1.0f, -1.0f};
  v4f nv = vfma4(al, dv, c4);
  return __builtin_elementwise_min(__builtin_elementwise_max(nv, mone), one);
}

// LDS float layout:
//   S0[2] : 32768 @ 0/16384 | S1[2] : 4096 @ 32768/34816 | S2[2] : 512 @ 36864/37120
//   total = 37376 floats = 149504 B -> 1 block/CU; 512 thr = 2 waves/SIMD.
extern "C" __global__ void __launch_bounds__(512, 2)
nca_fused(const float* __restrict__ x, const float* __restrict__ w1,
          const float* __restrict__ b1, const float* __restrict__ w2,
          const float* __restrict__ b2, const float* __restrict__ cw,
          const float* __restrict__ cb, float* __restrict__ out) {
  extern __shared__ float4 ldsv[];
  float* lds = (float*)ldsv;
  const int tid = threadIdx.x;
  const int bid = blockIdx.x;

  float* S0[2] = {lds, lds + 16384};
  float* S1[2] = {lds + 32768, lds + 34816};
  float* S2[2] = {lds + 36864, lds + 37120};

  // zero-init all state (LDS undefined at launch)
#pragma unroll 1
  for (int i = tid; i < 37376 / 4; i += 512) ldsv[i] = make_float4(0.f, 0.f, 0.f, 0.f);
  __syncthreads();

  // set_input: pattern = (x > 0.5) into channel 0 of d=8 slab of level 0
  if (tid < 256) {
    float v = x[bid * 256 + tid];
    int i = tid >> 4, j = tid & 15;
    S0[0][ix0(i, j, 8)] = (v > 0.5f) ? 1.0f : 0.0f;
  }
  __syncthreads();

  // d-major decomposition: WAVE owns a d-slab (cone axis is d).
  const int gd = tid >> 6;        // wave id 0..7 -> L0 d in {2gd,2gd+1}, L1 d = gd
  const int ga = (tid >> 3) & 7;
  const int gb = tid & 7;

  // register-resident copy of this thread's 2x2x2 L0 group (== LDS copy)
  v4f s[8];
#pragma unroll
  for (int cell = 0; cell < 8; ++cell)
    s[cell] = ld4(S0[0] + ix0(2 * ga + (cell >> 2), 2 * gb + ((cell >> 1) & 1),
                              2 * gd + (cell & 1)));

#pragma unroll 1
  for (int t = 0; t < 15; ++t) {
    const float* s0c = S0[t & 1];
    float* s0n = S0[(t & 1) ^ 1];
    const float* s1c = S1[t & 1];
    float* s1n = S1[(t & 1) ^ 1];
    const float* s2c = S2[t & 1];
    float* s2n = S2[(t & 1) ^ 1];

    // exact compute-cones; wave-uniform scalar selects
    const int dlo0 = t == 0 ? 7 : t == 1 ? 6 : t == 2 ? 5 : t == 3 ? 4 : t == 4 ? 2 : 0;
    const int dhi0 = t == 0 ? 9 : t == 1 ? 10 : t == 2 ? 11 : t == 3 ? 13 : 15;
    const int l1lo = t == 0 ? 4 : t == 1 ? 3 : t == 2 ? 2 : t == 3 ? 1 : 0;
    const int l1hi = t == 0 ? 4 : t == 1 ? 5 : t == 2 ? 6 : t == 3 ? 7 : 7;

    // below-pool for L1, summed from PRE-update regs in q-order (== r11 order)
    v4f blsum = {0.f, 0.f, 0.f, 0.f};
#pragma unroll
    for (int q = 0; q < 8; ++q) blsum = blsum + s[q];

    // ---------------- level 0: 2x2x2 group per thread, t<=12, cone-gated ----
    if (t < 13 && 2 * gd + 1 >= dlo0 && 2 * gd <= dhi0) {
      const float* W1 = w1;  // (16,32) level 0
      const float* W2 = w2;  // (32,4)
      // 'above' fold: bias + above-contribution once for all 8 cells
      v4f ab = ld4(s1c + ix1(ga, gb, gd));
      const v2f* b1v = (const v2f*)b1;
      v2f acc[16];
#pragma unroll
      for (int j = 0; j < 16; ++j) acc[j] = b1v[j];
      fma_row16(acc, ab.xx, W1 + 12 * 32);
      fma_row16(acc, ab.yy, W1 + 13 * 32);
      fma_row16(acc, ab.zz, W1 + 14 * 32);
      fma_row16(acc, ab.ww, W1 + 15 * 32);

      // phase A: all 8 neighbor sums from OLD state (regs intra, LDS halo)
      v4f nbv[8];
#pragma unroll
      for (int cell = 0; cell < 8; ++cell) {
        const int da = cell >> 2, db = (cell >> 1) & 1, dd = cell & 1;
        const int a = 2 * ga + da, b = 2 * gb + db, d = 2 * gd + dd;
        v4f nb = {0.f, 0.f, 0.f, 0.f};
        if (da == 1) nb = nb + s[cell ^ 4];          // a-1 (intra, always valid)
        else if (ga > 0) nb = nb + ld4(s0c + ix0(a - 1, b, d));
        if (da == 0) nb = nb + s[cell ^ 4];          // a+1 (intra)
        else if (ga < 7) nb = nb + ld4(s0c + ix0(a + 1, b, d));
        if (db == 1) nb = nb + s[cell ^ 2];          // b-1 (intra)
        else if (gb > 0) nb = nb + ld4(s0c + ix0(a, b - 1, d));
        if (db == 0) nb = nb + s[cell ^ 2];          // b+1 (intra)
        else if (gb < 7) nb = nb + ld4(s0c + ix0(a, b + 1, d));
        if (dd == 1) nb = nb + s[cell ^ 1];          // d-1 (intra)
        else if (gd > 0) nb = nb + ld4(s0c + ix0(a, b, d - 1));
        if (dd == 0) nb = nb + s[cell ^ 1];          // d+1 (intra)
        else if (gd < 7) nb = nb + ld4(s0c + ix0(a, b, d + 1));
        nbv[cell] = nb;
      }

      // phase B: MLP + commit (regs + LDS), 2 hid[16] live
#pragma unroll 2
      for (int cell = 0; cell < 8; ++cell) {
        const int a = 2 * ga + (cell >> 2);
        const int b = 2 * gb + ((cell >> 1) & 1);
        const int d = 2 * gd + (cell & 1);
        v4f c4 = s[cell];
        v2f hid[16];
        p_rows_init(hid, acc, c4, nbv[cell], W1);  // below == 0 at level 0
        v4f nv = mlp_tail(hid, W2, b2, c4);
        st4(s0n + ix0(a, b, d), nv);
        s[cell] = nv;
      }
    }

    // ---------------- level 1: one cell per thread, t<=13, cone-gated -------
    if (t < 14 && gd >= l1lo && gd <= l1hi) {
      const float* W1 = w1 + 512;
      const float* W2 = w2 + 128;
      const float* B1 = b1 + 32;
      const float* B2 = b2 + 4;
      int a = ga, b = gb, d = gd;
      v4f c4 = ld4(s1c + ix1(a, b, d));
      v4f nb = {0.f, 0.f, 0.f, 0.f};
      if (a > 0) nb = nb + ld4(s1c + ix1(a - 1, b, d));
      if (a < 7) nb = nb + ld4(s1c + ix1(a + 1, b, d));
      if (b > 0) nb = nb + ld4(s1c + ix1(a, b - 1, d));
      if (b < 7) nb = nb + ld4(s1c + ix1(a, b + 1, d));
      if (d > 0) nb = nb + ld4(s1c + ix1(a, b, d - 1));
      if (d < 7) nb = nb + ld4(s1c + ix1(a, b, d + 1));
      // below = avgpool2(old level 0) == blsum/8 (regs, pre-update)
      v4f eighth = {0.125f, 0.125f, 0.125f, 0.125f};
      v4f bl = blsum * eighth;
      v4f ab = ld4(s2c + ix2(a >> 1, b >> 1, d >> 1));
      const v2f* B1v = (const v2f*)B1;
      v2f hid[16];
#pragma unroll
      for (int j = 0; j < 16; ++j) hid[j] = B1v[j];
      p_rows(hid, c4, nb, W1);
      fma_row16(hid, bl.xx, W1 + 8 * 32);
      fma_row16(hid, bl.yy, W1 + 9 * 32);
      fma_row16(hid, bl.zz, W1 + 10 * 32);
      fma_row16(hid, bl.ww, W1 + 11 * 32);
      fma_row16(hid, ab.xx, W1 + 12 * 32);
      fma_row16(hid, ab.yy, W1 + 13 * 32);
      fma_row16(hid, ab.zz, W1 + 14 * 32);
      fma_row16(hid, ab.ww, W1 + 15 * 32);
      st4(s1n + ix1(a, b, d), mlp_tail(hid, W2, B2, c4));
    }

    // ------- level 2: one cell per thread, wave 0 (gd=0: cone-idle early) ---
    if (t > 0 && tid < 64) {
      const float* W1 = w1 + 1024;
      const float* W2 = w2 + 256;
      const float* B1 = b1 + 64;
      const float* B2 = b2 + 8;
      int a = tid >> 4, b = (tid >> 2) & 3, d = tid & 3;
      v4f c4 = ld4(s2c + ix2(a, b, d));
      v4f nb = {0.f, 0.f, 0.f, 0.f};
      if (a > 0) nb = nb + ld4(s2c + ix2(a - 1, b, d));
      if (a < 3) nb = nb + ld4(s2c + ix2(a + 1, b, d));
      if (b > 0) nb = nb + ld4(s2c + ix2(a, b - 1, d));
      if (b < 3) nb = nb + ld4(s2c + ix2(a, b + 1, d));
      if (d > 0) nb = nb + ld4(s2c + ix2(a, b, d - 1));
      if (d < 3) nb = nb + ld4(s2c + ix2(a, b, d + 1));
      v4f bl = {0.f, 0.f, 0.f, 0.f};
#pragma unroll
      for (int q = 0; q < 8; ++q)
        bl = bl + ld4(s1c + ix1(2 * a + (q >> 2), 2 * b + ((q >> 1) & 1), 2 * d + (q & 1)));
      v4f eighth = {0.125f, 0.125f, 0.125f, 0.125f};
      bl = bl * eighth;
      const v2f* B1v = (const v2f*)B1;
      v2f hid[16];
#pragma unroll
      for (int j = 0; j < 16; ++j) hid[j] = B1v[j];
      p_rows(hid, c4, nb, W1);
      fma_row16(hid, bl.xx, W1 + 8 * 32);
      fma_row16(hid, bl.yy, W1 + 9 * 32);
      fma_row16(hid, bl.zz, W1 + 10 * 32);
      fma_row16(hid, bl.ww, W1 + 11 * 32);
      // above == 0 at top level: rows 12..15 skipped
      st4(s2n + ix2(a, b, d), mlp_tail(hid, W2, B2, c4));
    }

    __syncthreads();  // single barrier per step: all reads from [cur], writes to [nxt]
  }

  // ---------------- classifier: feats(256) @ cls_w(256,10) + cls_b ----------------
  // 15 steps -> final S2 lives in buffer 1. Double accumulation keeps the
  // 256-long dot well inside the absmax threshold.
  if (tid < 256) {
    double v = (double)S2[1][tid];  // linear index == ((a*4+b)*4+d)*4+c == reshape order
    const float* wr = cw + tid * 10;
    double p[10];
#pragma unroll
    for (int o = 0; o < 10; ++o) p[o] = v * (double)wr[o];
#pragma unroll
    for (int off = 32; off > 0; off >>= 1) {
#pragma unroll
      for (int o = 0; o < 10; ++o) p[o] += __shfl_down(p[o], off);
    }
    if ((tid & 63) == 0) {
      double* red = (double*)S2[0];  // buffer 0 is dead after the loop; 40 doubles
      int wv = tid >> 6;
#pragma unroll
      for (int o = 0; o < 10; ++o) red[wv * 10 + o] = p[o];
    }
  }
  __syncthreads();
  if (tid < 10) {
    const double* red = (const double*)S2[0];
    double r = (double)cb[tid] + red[tid] + red[10 + tid] + red[20 + tid] + red[30 + tid];
    out[bid * 10 + tid] = (float)r;
  }
}

extern "C" void kernel_launch(void* const* d_in, const int* in_sizes, int n_in,
                              void* d_out, int out_size, void* d_ws, size_t ws_size,
                              hipStream_t stream) {
  const float* x = (const float*)d_in[0];
  const float* w1 = (const float*)d_in[1];
  const float* b1 = (const float*)d_in[2];
  const float* w2 = (const float*)d_in[3];
  const float* b2 = (const float*)d_in[4];
  const float* cw = (const float*)d_in[5];
  const float* cb = (const float*)d_in[6];
  float* out = (float*)d_out;

  const int B = in_sizes[0] / 256;                // 2048
  const size_t shmem = 37376 * sizeof(float);     // 149504 B > 64 KiB: opt in
  // host-side metadata call, not a stream op -> graph-capture safe; idempotent
  hipFuncSetAttribute((const void*)nca_fused, hipFuncAttributeMaxDynamicSharedMemorySize,
                      (int)shmem);
  nca_fused<<<dim3(B), dim3(512), shmem, stream>>>(x, w1, b1, w2, b2, cw, cb, out);
}

// Round 14
// 2540.545 us; speedup vs baseline: 1.3225x; 1.3225x over previous
//
#include <hip/hip_runtime.h>

#define NCA_ALPHA 0.1f

// r14 = r11 (best, 2515us) + two low-register-pressure deltas:
//  1) L1's below-pool folded into the L0 cell loop: blsum += c4 while the old
//     cells are being loaded anyway (+4 VGPR) -> L1 drops 8 ds_read_b128 +
//     addressing. Cone-safe: a wave with L0 gate off has provably-zero L0
//     cells (monotone cones + ping-pong induction) -> blsum=0 correct. At
//     t=13 (L0 dead-skipped, pool live) fall back to the r11 LDS pool read.
//  2) mlp_tail chain split: d01/d23 were 32-deep serial FMA chains; split by
//     j-parity into 4 chains of 16 (+4 VGPR). FLOP order of the final sums
//     changes (threshold 3e-6 >> expected ~1e-7 drift).
// r13 lesson: VGPR budget at 512thr is hard-capped at 128; any live-set
// expansion beyond ~110 spills (1.5GB scratch). Both deltas stay tiny.
//
// Light cones (exact): L0 t: t0 [7,9] t1 [6,10] t2 [5,11] t3 [4,13] t4 [2,15]
// else full; L1 t: t0 {4} t1 [3,5] t2 [2,6] t3 [1,7] else full.
// Dead steps: L0 t<=12, L1 t<=13, L2 t>=1.
typedef float v2f __attribute__((ext_vector_type(2)));
typedef float v4f __attribute__((ext_vector_type(4)));

__device__ __forceinline__ v4f ld4(const float* p) { return *(const v4f*)p; }
__device__ __forceinline__ void st4(float* p, v4f v) { *(v4f*)p = v; }
__device__ __forceinline__ v2f vfma2(v2f a, v2f b, v2f c) {
  return __builtin_elementwise_fma(a, b, c);
}
__device__ __forceinline__ v4f vfma4(v4f a, v4f b, v4f c) {
  return __builtin_elementwise_fma(a, b, c);
}

// r11 swizzled indices (measured-best base)
__device__ __forceinline__ int ix0(int a, int b, int d) {
  return (((a * 16 + b) * 16 + d) * 4) ^ ((((a >> 1) ^ (b >> 1)) & 7) << 2);
}
__device__ __forceinline__ int ix1(int a, int b, int d) {
  return (((a * 8 + b) * 8 + d) * 4) ^ (((a ^ b) & 7) << 2);
}
__device__ __forceinline__ int ix2(int a, int b, int d) { return ((a * 4 + b) * 4 + d) * 4; }

// h[j] += vv * w[j] over 16 pairs; w is wave-uniform (s_load pairs), vv a splat.
__device__ __forceinline__ void fma_row16(v2f h[16], v2f vv, const float* __restrict__ w) {
  const v2f* wv = (const v2f*)w;
#pragma unroll
  for (int j = 0; j < 16; ++j) h[j] = vfma2(vv, wv[j], h[j]);
}

// 8 perception rows, accumulate-only (h pre-initialized with bias/fold).
__device__ __forceinline__ void p_rows(v2f h[16], v4f c4, v4f nb, const float* __restrict__ W1) {
  v4f m6 = {-6.0f, -6.0f, -6.0f, -6.0f};
  v4f lap = vfma4(m6, c4, nb);
  fma_row16(h, c4.xx, W1 + 0);
  fma_row16(h, lap.xx, W1 + 32);
  fma_row16(h, c4.yy, W1 + 64);
  fma_row16(h, lap.yy, W1 + 96);
  fma_row16(h, c4.zz, W1 + 128);
  fma_row16(h, lap.zz, W1 + 160);
  fma_row16(h, c4.ww, W1 + 192);
  fma_row16(h, lap.ww, W1 + 224);
}

// Same but row 0 initializes h from acc (saves the 16-pair copy).
__device__ __forceinline__ void p_rows_init(v2f h[16], const v2f acc[16], v4f c4, v4f nb,
                                            const float* __restrict__ W1) {
  v4f m6 = {-6.0f, -6.0f, -6.0f, -6.0f};
  v4f lap = vfma4(m6, c4, nb);
  const v2f* w0 = (const v2f*)W1;
#pragma unroll
  for (int j = 0; j < 16; ++j) h[j] = vfma2(c4.xx, w0[j], acc[j]);
  fma_row16(h, lap.xx, W1 + 32);
  fma_row16(h, c4.yy, W1 + 64);
  fma_row16(h, lap.yy, W1 + 96);
  fma_row16(h, c4.zz, W1 + 128);
  fma_row16(h, lap.zz, W1 + 160);
  fma_row16(h, c4.ww, W1 + 192);
  fma_row16(h, lap.ww, W1 + 224);
}

// relu + (32x4) second layer + residual + clip.
// CHAIN-SPLIT: even/odd-j partial accumulators halve the serial FMA depth
// (32 -> 16 per chain). Even chain carries the bias; odd starts at 0.
__device__ __forceinline__ v4f mlp_tail(const v2f h[16], const float* __restrict__ W2,
                                        const float* __restrict__ B2, v4f c4) {
  const v2f* w = (const v2f*)W2;
  const v2f* bv = (const v2f*)B2;
  v2f d01e = bv[0], d23e = bv[1];
  v2f d01o = {0.f, 0.f}, d23o = {0.f, 0.f};
  v2f z = {0.0f, 0.0f};
#pragma unroll
  for (int k = 0; k < 8; ++k) {
    v2f hr0 = __builtin_elementwise_max(h[2 * k], z);
    d01e = vfma2(hr0.xx, w[8 * k + 0], d01e);
    d23e = vfma2(hr0.xx, w[8 * k + 1], d23e);
    d01e = vfma2(hr0.yy, w[8 * k + 2], d01e);
    d23e = vfma2(hr0.yy, w[8 * k + 3], d23e);
    v2f hr1 = __builtin_elementwise_max(h[2 * k + 1], z);
    d01o = vfma2(hr1.xx, w[8 * k + 4], d01o);
    d23o = vfma2(hr1.xx, w[8 * k + 5], d23o);
    d01o = vfma2(hr1.yy, w[8 * k + 6], d01o);
    d23o = vfma2(hr1.yy, w[8 * k + 7], d23o);
  }
  v2f d01 = d01e + d01o, d23 = d23e + d23o;
  v4f dv = {d01.x, d01.y, d23.x, d23.y};
  v4f al = {NCA_ALPHA, NCA_ALPHA, NCA_ALPHA, NCA_ALPHA};
  v4f one = {1.0f, 1.0f, 1.0f, 1.0f};
  v4f mone = {-1.0f, -1.0f, -1.0f, -1.0f};
  v4f nv = vfma4(al, dv, c4);
  return __builtin_elementwise_min(__builtin_elementwise_max(nv, mone), one);
}

// LDS float layout:
//   S0[2] : 32768 @ 0/16384 | S1[2] : 4096 @ 32768/34816 | S2[2] : 512 @ 36864/37120
//   total = 37376 floats = 149504 B -> 1 block/CU; 512 thr = 2 waves/SIMD.
extern "C" __global__ void __launch_bounds__(512, 2)
nca_fused(const float* __restrict__ x, const float* __restrict__ w1,
          const float* __restrict__ b1, const float* __restrict__ w2,
          const float* __restrict__ b2, const float* __restrict__ cw,
          const float* __restrict__ cb, float* __restrict__ out) {
  extern __shared__ float4 ldsv[];
  float* lds = (float*)ldsv;
  const int tid = threadIdx.x;
  const int bid = blockIdx.x;

  float* S0[2] = {lds, lds + 16384};
  float* S1[2] = {lds + 32768, lds + 34816};
  float* S2[2] = {lds + 36864, lds + 37120};

  // zero-init all state (LDS undefined at launch)
#pragma unroll 1
  for (int i = tid; i < 37376 / 4; i += 512) ldsv[i] = make_float4(0.f, 0.f, 0.f, 0.f);
  __syncthreads();

  // set_input: pattern = (x > 0.5) into channel 0 of d=8 slab of level 0
  if (tid < 256) {
    float v = x[bid * 256 + tid];
    int i = tid >> 4, j = tid & 15;
    S0[0][ix0(i, j, 8)] = (v > 0.5f) ? 1.0f : 0.0f;
  }
  __syncthreads();

  // d-major decomposition: WAVE owns a d-slab (cone axis is d).
  const int gd = tid >> 6;        // wave id 0..7 -> L0 d in {2gd,2gd+1}, L1 d = gd
  const int ga = (tid >> 3) & 7;
  const int gb = tid & 7;

#pragma unroll 1
  for (int t = 0; t < 15; ++t) {
    const float* s0c = S0[t & 1];
    float* s0n = S0[(t & 1) ^ 1];
    const float* s1c = S1[t & 1];
    float* s1n = S1[(t & 1) ^ 1];
    const float* s2c = S2[t & 1];
    float* s2n = S2[(t & 1) ^ 1];

    // exact compute-cones; wave-uniform scalar selects
    const int dlo0 = t == 0 ? 7 : t == 1 ? 6 : t == 2 ? 5 : t == 3 ? 4 : t == 4 ? 2 : 0;
    const int dhi0 = t == 0 ? 9 : t == 1 ? 10 : t == 2 ? 11 : t == 3 ? 13 : 15;
    const int l1lo = t == 0 ? 4 : t == 1 ? 3 : t == 2 ? 2 : t == 3 ? 1 : 0;
    const int l1hi = t == 0 ? 4 : t == 1 ? 5 : t == 2 ? 6 : t == 3 ? 7 : 7;

    // pool accumulator: filled by the L0 loop from the old c4 values (q-order).
    // Gate-off waves leave it 0 == their provably-zero L0 region's pool.
    v4f blsum = {0.f, 0.f, 0.f, 0.f};

    // ---------------- level 0: 2x2x2 group per thread, t<=12, cone-gated ----
    if (t < 13 && 2 * gd + 1 >= dlo0 && 2 * gd <= dhi0) {
      const float* W1 = w1;  // (16,32) level 0
      const float* W2 = w2;  // (32,4)
      // 'above' fold: bias + above-contribution once for all 8 cells
      v4f ab = ld4(s1c + ix1(ga, gb, gd));
      const v2f* b1v = (const v2f*)b1;
      v2f acc[16];
#pragma unroll
      for (int j = 0; j < 16; ++j) acc[j] = b1v[j];
      fma_row16(acc, ab.xx, W1 + 12 * 32);
      fma_row16(acc, ab.yy, W1 + 13 * 32);
      fma_row16(acc, ab.zz, W1 + 14 * 32);
      fma_row16(acc, ab.ww, W1 + 15 * 32);

#pragma unroll 4
      for (int cell = 0; cell < 8; ++cell) {
        int a = 2 * ga + (cell >> 2);
        int b = 2 * gb + ((cell >> 1) & 1);
        int d = 2 * gd + (cell & 1);
        v4f c4 = ld4(s0c + ix0(a, b, d));
        blsum = blsum + c4;  // old value, q-order == r11's pool order
        v4f nb = {0.f, 0.f, 0.f, 0.f};
        if (a > 0) nb = nb + ld4(s0c + ix0(a - 1, b, d));
        if (a < 15) nb = nb + ld4(s0c + ix0(a + 1, b, d));
        if (b > 0) nb = nb + ld4(s0c + ix0(a, b - 1, d));
        if (b < 15) nb = nb + ld4(s0c + ix0(a, b + 1, d));
        if (d > 0) nb = nb + ld4(s0c + ix0(a, b, d - 1));
        if (d < 15) nb = nb + ld4(s0c + ix0(a, b, d + 1));
        v2f hid[16];
        p_rows_init(hid, acc, c4, nb, W1);  // below == 0 at level 0
        st4(s0n + ix0(a, b, d), mlp_tail(hid, W2, b2, c4));
      }
    }

    // ---------------- level 1: one cell per thread, t<=13, cone-gated -------
    if (t < 14 && gd >= l1lo && gd <= l1hi) {
      const float* W1 = w1 + 512;
      const float* W2 = w2 + 128;
      const float* B1 = b1 + 32;
      const float* B2 = b2 + 4;
      int a = ga, b = gb, d = gd;
      v4f c4 = ld4(s1c + ix1(a, b, d));
      v4f nb = {0.f, 0.f, 0.f, 0.f};
      if (a > 0) nb = nb + ld4(s1c + ix1(a - 1, b, d));
      if (a < 7) nb = nb + ld4(s1c + ix1(a + 1, b, d));
      if (b > 0) nb = nb + ld4(s1c + ix1(a, b - 1, d));
      if (b < 7) nb = nb + ld4(s1c + ix1(a, b + 1, d));
      if (d > 0) nb = nb + ld4(s1c + ix1(a, b, d - 1));
      if (d < 7) nb = nb + ld4(s1c + ix1(a, b, d + 1));
      // below = avgpool2(old level 0): from blsum when the L0 loop ran this
      // step (t<13; gate-off waves have zero pool == blsum). t==13: L0 was
      // dead-skipped but its state is live -> r11-style LDS pool read.
      v4f bl;
      v4f eighth = {0.125f, 0.125f, 0.125f, 0.125f};
      if (t < 13) {
        bl = blsum * eighth;
      } else {
        v4f ps = {0.f, 0.f, 0.f, 0.f};
#pragma unroll
        for (int q = 0; q < 8; ++q)
          ps = ps + ld4(s0c + ix0(2 * a + (q >> 2), 2 * b + ((q >> 1) & 1), 2 * d + (q & 1)));
        bl = ps * eighth;
      }
      v4f ab = ld4(s2c + ix2(a >> 1, b >> 1, d >> 1));
      const v2f* B1v = (const v2f*)B1;
      v2f hid[16];
#pragma unroll
      for (int j = 0; j < 16; ++j) hid[j] = B1v[j];
      p_rows(hid, c4, nb, W1);
      fma_row16(hid, bl.xx, W1 + 8 * 32);
      fma_row16(hid, bl.yy, W1 + 9 * 32);
      fma_row16(hid, bl.zz, W1 + 10 * 32);
      fma_row16(hid, bl.ww, W1 + 11 * 32);
      fma_row16(hid, ab.xx, W1 + 12 * 32);
      fma_row16(hid, ab.yy, W1 + 13 * 32);
      fma_row16(hid, ab.zz, W1 + 14 * 32);
      fma_row16(hid, ab.ww, W1 + 15 * 32);
      st4(s1n + ix1(a, b, d), mlp_tail(hid, W2, B2, c4));
    }

    // ------- level 2: one cell per thread, wave 0 (gd=0: cone-idle early) ---
    if (t > 0 && tid < 64) {
      const float* W1 = w1 + 1024;
      const float* W2 = w2 + 256;
      const float* B1 = b1 + 64;
      const float* B2 = b2 + 8;
      int a = tid >> 4, b = (tid >> 2) & 3, d = tid & 3;
      v4f c4 = ld4(s2c + ix2(a, b, d));
      v4f nb = {0.f, 0.f, 0.f, 0.f};
      if (a > 0) nb = nb + ld4(s2c + ix2(a - 1, b, d));
      if (a < 3) nb = nb + ld4(s2c + ix2(a + 1, b, d));
      if (b > 0) nb = nb + ld4(s2c + ix2(a, b - 1, d));
      if (b < 3) nb = nb + ld4(s2c + ix2(a, b + 1, d));
      if (d > 0) nb = nb + ld4(s2c + ix2(a, b, d - 1));
      if (d < 3) nb = nb + ld4(s2c + ix2(a, b, d + 1));
      v4f bl = {0.f, 0.f, 0.f, 0.f};
#pragma unroll
      for (int q = 0; q < 8; ++q)
        bl = bl + ld4(s1c + ix1(2 * a + (q >> 2), 2 * b + ((q >> 1) & 1), 2 * d + (q & 1)));
      v4f eighth = {0.125f, 0.125f, 0.125f, 0.125f};
      bl = bl * eighth;
      const v2f* B1v = (const v2f*)B1;
      v2f hid[16];
#pragma unroll
      for (int j = 0; j < 16; ++j) hid[j] = B1v[j];
      p_rows(hid, c4, nb, W1);
      fma_row16(hid, bl.xx, W1 + 8 * 32);
      fma_row16(hid, bl.yy, W1 + 9 * 32);
      fma_row16(hid, bl.zz, W1 + 10 * 32);
      fma_row16(hid, bl.ww, W1 + 11 * 32);
      // above == 0 at top level: rows 12..15 skipped
      st4(s2n + ix2(a, b, d), mlp_tail(hid, W2, B2, c4));
    }

    __syncthreads();  // single barrier per step: all reads from [cur], writes to [nxt]
  }

  // ---------------- classifier: feats(256) @ cls_w(256,10) + cls_b ----------------
  // 15 steps -> final S2 lives in buffer 1. Double accumulation keeps the
  // 256-long dot well inside the absmax threshold.
  if (tid < 256) {
    double v = (double)S2[1][tid];  // linear index == ((a*4+b)*4+d)*4+c == reshape order
    const float* wr = cw + tid * 10;
    double p[10];
#pragma unroll
    for (int o = 0; o < 10; ++o) p[o] = v * (double)wr[o];
#pragma unroll
    for (int off = 32; off > 0; off >>= 1) {
#pragma unroll
      for (int o = 0; o < 10; ++o) p[o] += __shfl_down(p[o], off);
    }
    if ((tid & 63) == 0) {
      double* red = (double*)S2[0];  // buffer 0 is dead after the loop; 40 doubles
      int wv = tid >> 6;
#pragma unroll
      for (int o = 0; o < 10; ++o) red[wv * 10 + o] = p[o];
    }
  }
  __syncthreads();
  if (tid < 10) {
    const double* red = (const double*)S2[0];
    double r = (double)cb[tid] + red[tid] + red[10 + tid] + red[20 + tid] + red[30 + tid];
    out[bid * 10 + tid] = (float)r;
  }
}

extern "C" void kernel_launch(void* const* d_in, const int* in_sizes, int n_in,
                              void* d_out, int out_size, void* d_ws, size_t ws_size,
                              hipStream_t stream) {
  const float* x = (const float*)d_in[0];
  const float* w1 = (const float*)d_in[1];
  const float* b1 = (const float*)d_in[2];
  const float* w2 = (const float*)d_in[3];
  const float* b2 = (const float*)d_in[4];
  const float* cw = (const float*)d_in[5];
  const float* cb = (const float*)d_in[6];
  float* out = (float*)d_out;

  const int B = in_sizes[0] / 256;                // 2048
  const size_t shmem = 37376 * sizeof(float);     // 149504 B > 64 KiB: opt in
  // host-side metadata call, not a stream op -> graph-capture safe; idempotent
  hipFuncSetAttribute((const void*)nca_fused, hipFuncAttributeMaxDynamicSharedMemorySize,
                      (int)shmem);
  nca_fused<<<dim3(B), dim3(512), shmem, stream>>>(x, w1, b1, w2, b2, cw, cb, out);
}